// Round 10
// baseline (530.711 us; speedup 1.0000x reference)
//
#include <hip/hip_runtime.h>
#include <hip/hip_bf16.h>

// Problem constants
#define ROWS  4096      // B*T
#define DDIM  1024
#define DKDIM 256
#define NKEYS 32768
#define DMDIM 256
#define KN    8
#define FDIM  2048      // KN*DM
#define CAPS  1536      // knn LDS candidate buffer (>= 8*SLOT)
#define SLOT  184       // per-(row, cg-slice) candidate segment (harness-passed in R1)
#define SURV  128       // stage-1 survivors (mean ~30 at 12.25, max << 128)
#define SURV2 96        // stage-2 survivors (mean ~21)
#define MARGIN   16.0f  // push margin, s-units (proven R2 value)
#define REFILT_M 12.25f // stage-1: 10.82 exact depth + 1.2 bf16 err + 0.05 quant
#define EXACT_M  109.0f // stage-2, logit units: 7*13.8 + ln(1e5)

typedef float  f32x4  __attribute__((ext_vector_type(4)));
typedef __bf16 bf16x8 __attribute__((ext_vector_type(8)));

static __device__ __forceinline__ unsigned enc_f32(float f) {
  unsigned u = __float_as_uint(f);
  return u ^ ((unsigned)((int)u >> 31) | 0x80000000u);
}
static __device__ __forceinline__ float dec_f32(unsigned u) {
  unsigned b = (u & 0x80000000u) ? (u ^ 0x80000000u) : ~u;
  return __uint_as_float(b);
}
static __device__ __forceinline__ unsigned short f2bf(float f) {
  unsigned u = __float_as_uint(f);
  u += 0x7FFFu + ((u >> 16) & 1u);          // RNE truncate to bf16
  return (unsigned short)(u >> 16);
}
// pack candidate: score quantized (1/64 res) high, key id (15 bits) low
static __device__ __forceinline__ unsigned pack_cand(float s, int n) {
  float q = (s + 1024.f) * 64.f;
  int u = (int)q;
  u = u < 0 ? 0 : (u > 131071 ? 131071 : u);
  return ((unsigned)u << 15) | (unsigned)n;
}
static __device__ __forceinline__ float cand_score(unsigned p) {
  return (float)(p >> 15) * (1.f / 64.f) - 1024.f;
}
static __device__ __forceinline__ void gld16(const void* g, void* l) {
  __builtin_amdgcn_global_load_lds((const __attribute__((address_space(1))) void*)g,
                                   (__attribute__((address_space(3))) void*)l, 16, 0, 0);
}

// ---------------------------------------------------------------- fused prep:
// blocks [0,8192): keys->bf16 + k2 ; [8192,10240): Wout->bf16 ; [10240,10256): zero rowmax
__global__ __launch_bounds__(256) void prep_all(const float* __restrict__ keys,
                                                const float* __restrict__ Wout,
                                                unsigned short* __restrict__ kbf,
                                                float* __restrict__ k2,
                                                unsigned short* __restrict__ wbf,
                                                unsigned* __restrict__ rowmax) {
  const int b = blockIdx.x, t = threadIdx.x;
  if (b < 8192) {
    const int row = b * 4 + (t >> 6);
    const int ln  = t & 63;
    const float4 v = *(const float4*)(keys + (size_t)row * DKDIM + ln * 4);
    ushort4 o;
    o.x = f2bf(v.x); o.y = f2bf(v.y); o.z = f2bf(v.z); o.w = f2bf(v.w);
    *(ushort4*)(kbf + (size_t)row * DKDIM + ln * 4) = o;
    float ss = v.x*v.x + v.y*v.y + v.z*v.z + v.w*v.w;
    for (int off = 32; off; off >>= 1) ss += __shfl_down(ss, off);
    if (ln == 0) k2[row] = ss;
  } else if (b < 10240) {
    const int i = (b - 8192) * 256 + t;      // i < 524288 = DDIM*FDIM/4
    const float4 v = *(const float4*)(Wout + (size_t)i * 4);
    ushort4 o;
    o.x = f2bf(v.x); o.y = f2bf(v.y); o.z = f2bf(v.z); o.w = f2bf(v.w);
    *(ushort4*)(wbf + (size_t)i * 4) = o;
  } else {
    rowmax[(b - 10240) * 256 + t] = 0u;      // 4096 rowmax entries (cnt fully overwritten)
  }
}

// ---------------------------------------------------------------- q = x @ W_in^T + b_in (fp32)
__global__ __launch_bounds__(256) void qproj(const float* __restrict__ x,
                                             const float* __restrict__ Win,
                                             const float* __restrict__ bin,
                                             float* __restrict__ qf,
                                             unsigned short* __restrict__ qbf) {
  __shared__ __align__(16) float As[64][68];
  __shared__ __align__(16) float Bs[64][68];
  const int bm = blockIdx.x, bn = blockIdx.y;
  const int t  = threadIdx.x;
  const int tx = t & 15, ty = t >> 4;
  float acc[4][4] = {};
  for (int ks = 0; ks < 16; ++ks) {
    __syncthreads();
    for (int l = t; l < 1024; l += 256) {
      const int row = l >> 4, kc = l & 15;
      *(float4*)(&As[row][kc * 4]) =
          *(const float4*)(x + (size_t)(bm * 64 + row) * DDIM + ks * 64 + kc * 4);
      *(float4*)(&Bs[row][kc * 4]) =
          *(const float4*)(Win + (size_t)(bn * 64 + row) * DDIM + ks * 64 + kc * 4);
    }
    __syncthreads();
    for (int kk = 0; kk < 64; kk += 4) {
      float4 av[4], bv[4];
#pragma unroll
      for (int i = 0; i < 4; ++i) av[i] = *(const float4*)(&As[ty * 4 + i][kk]);
#pragma unroll
      for (int j = 0; j < 4; ++j) bv[j] = *(const float4*)(&Bs[tx * 4 + j][kk]);
#pragma unroll
      for (int i = 0; i < 4; ++i)
#pragma unroll
        for (int j = 0; j < 4; ++j)
          acc[i][j] += av[i].x * bv[j].x + av[i].y * bv[j].y +
                       av[i].z * bv[j].z + av[i].w * bv[j].w;
    }
  }
#pragma unroll
  for (int i = 0; i < 4; ++i)
#pragma unroll
    for (int j = 0; j < 4; ++j) {
      const int m = bm * 64 + ty * 4 + i, n = bn * 64 + tx * 4 + j;
      const float q = acc[i][j] + bin[n];
      qf[(size_t)m * DKDIM + n] = q;
      qbf[(size_t)m * DKDIM + n] = f2bf(q);
    }
}

// ---------------------------------------------------------------- shared MFMA tile (R8-verified, used by out_gemm)
template <int KD>
static __device__ __forceinline__ void gemm_tile(const unsigned short* __restrict__ A,
                                                 const unsigned short* __restrict__ B,
                                                 int bm, int bn,
                                                 unsigned short* As, unsigned short* Bs,
                                                 f32x4 acc[4][4]) {
  const int tid  = threadIdx.x;
  const int lane = tid & 63, wave = tid >> 6;
  const int quad = lane >> 4, l15 = lane & 15;
  const int wr = (wave >> 1) * 64, wc = (wave & 1) * 64;
  const int srow = tid >> 2;
  const int scg  = (tid & 3) ^ ((srow >> 1) & 3);        // swizzled source slot
  const int qa   = quad ^ ((l15 >> 1) & 3);              // swizzled read slot
  const unsigned short* gA = A + (size_t)(bm * 128 + srow) * KD + scg * 8;
  const unsigned short* gB = B + (size_t)(bn * 128 + srow) * KD + scg * 8;
  for (int ks = 0; ks < KD / 32; ++ks) {
    __syncthreads();
    gld16(gA + ks * 32,                     As + tid * 8);
    gld16(gA + (size_t)64 * KD + ks * 32,   As + 2048 + tid * 8);
    gld16(gB + ks * 32,                     Bs + tid * 8);
    gld16(gB + (size_t)64 * KD + ks * 32,   Bs + 2048 + tid * 8);
    __syncthreads();
    bf16x8 af[4], bfr[4];
#pragma unroll
    for (int i = 0; i < 4; ++i)
      af[i] = *(const bf16x8*)(As + (wr + i * 16 + l15) * 32 + qa * 8);
#pragma unroll
    for (int j = 0; j < 4; ++j)
      bfr[j] = *(const bf16x8*)(Bs + (wc + j * 16 + l15) * 32 + qa * 8);
#pragma unroll
    for (int i = 0; i < 4; ++i)
#pragma unroll
      for (int j = 0; j < 4; ++j)
        acc[i][j] = __builtin_amdgcn_mfma_f32_16x16x32_bf16(af[i], bfr[j], acc[i][j], 0, 0, 0);
  }
}

// ---------------------------------------------------------------- fused score + select (v10)
// v9 structure with the drain moved to the only safe place. Per tile:
//   1. loop-top __syncthreads (drains prior stage, publishes B)
//   2. issue rstale + k2v loads (used ~3000 cyc later -> fully hidden)
//   3. MFMA phase, barrier-free (no DMA pending -> ds_reads clean)
//   4. epilogue with R1-proven STALE rowmax: fire-and-forget atomicMax (no return wait),
//      thr = fmax(lmax, dec(rstale)) - MARGIN  (stale max only lowers thr -> superset of
//      pushes -> correct; R1 passed with identical scheme & SLOT)
//   5. pushes (thr ds_read + pcnt LDS atomic + cand stores) -- NO pending DMA anywhere
//   6. stage next B tile LAST (nothing follows -> no alias-drain; exposed cost = one
//      64KB-from-L2 drain at next loop-top barrier)
// v9's mistake: stage BEFORE pushes -> backend can't disambiguate DMA-writes-to-Bs from the
// pcnt LDS atomic -> vmcnt(0) before the pushes -> full stage exposed serially per tile,
// plus a returning cross-XCD atomicMax between two barriers (235 us, MfmaUtil 11.5%).
__global__ __launch_bounds__(256) void score_select(const unsigned short* __restrict__ qbf,
                                                    const unsigned short* __restrict__ kbf,
                                                    const float* __restrict__ k2,
                                                    unsigned* __restrict__ rowmax,
                                                    int* __restrict__ cnt,
                                                    unsigned* __restrict__ cand) {
  __shared__ __align__(16) unsigned short As[8 * 4096];   // 64 KB persistent A: [ks][128 rows][4 slots]
  __shared__ __align__(16) unsigned short Bs[8 * 4096];   // 64 KB current B tile (128 keys)
  __shared__ float wm[128][2];
  __shared__ float thr[128];
  __shared__ int   pcnt[128];
  const int cg = blockIdx.x, bm = blockIdx.y;
  const int t = threadIdx.x;
  const int lane = t & 63, wave = t >> 6;
  const int quad = lane >> 4, l15 = lane & 15;
  const int wr = (wave >> 1) * 64, wc = (wave & 1) * 64;
  const int srow = t >> 2;
  const int scg  = (t & 3) ^ ((srow >> 1) & 3);           // R8 swizzled source slot
  const int qa   = quad ^ ((l15 >> 1) & 3);               // R8 swizzled read slot

  if (t < 128) pcnt[t] = 0;

  // stage A once + B tile 0 (32 gld16 in flight; drained at first loop-top barrier)
  {
    const unsigned short* gA = qbf + (size_t)(bm * 128 + srow) * DKDIM + scg * 8;
#pragma unroll
    for (int ks = 0; ks < 8; ++ks) {
      gld16(gA + ks * 32,                      As + ks * 4096 + t * 8);
      gld16(gA + (size_t)64 * DKDIM + ks * 32, As + ks * 4096 + 2048 + t * 8);
    }
    const unsigned short* gB = kbf + ((size_t)cg * 4096 + srow) * DKDIM + scg * 8;
#pragma unroll
    for (int ks = 0; ks < 8; ++ks) {
      gld16(gB + ks * 32,                      Bs + ks * 4096 + t * 8);
      gld16(gB + (size_t)64 * DKDIM + ks * 32, Bs + ks * 4096 + 2048 + t * 8);
    }
  }

  float lmax = -3.4e38f;                                   // running own row max (t<128)
  f32x4 acc[4][4] = {};
  for (int tile = 0; tile < 32; ++tile) {
    __syncthreads();                 // drain staging, publish B(tile) (+A, pcnt at tile 0)
    // early issue: stale rowmax (uniform) + k2 for this tile; waits land after MFMA phase
    const unsigned rstale = rowmax[bm * 128 + (t & 127)];
    float k2v[4];
#pragma unroll
    for (int j = 0; j < 4; ++j) k2v[j] = k2[cg * 4096 + tile * 128 + wc + j * 16 + l15];
    // 128 MFMAs, barrier-free
#pragma unroll
    for (int ks = 0; ks < 8; ++ks) {
      bf16x8 af[4], bv[4];
#pragma unroll
      for (int i = 0; i < 4; ++i)
        af[i] = *(const bf16x8*)(As + ks * 4096 + (wr + i * 16 + l15) * 32 + qa * 8);
#pragma unroll
      for (int j = 0; j < 4; ++j)
        bv[j] = *(const bf16x8*)(Bs + ks * 4096 + (wc + j * 16 + l15) * 32 + qa * 8);
#pragma unroll
      for (int i = 0; i < 4; ++i)
#pragma unroll
        for (int j = 0; j < 4; ++j)
          acc[i][j] = __builtin_amdgcn_mfma_f32_16x16x32_bf16(af[i], bv[j], acc[i][j], 0, 0, 0);
    }
    // ---------------- epilogue for this 128-key tile ----------------
#pragma unroll
    for (int i = 0; i < 4; ++i)
#pragma unroll
      for (int r = 0; r < 4; ++r) {
        float v = -3.4e38f;
#pragma unroll
        for (int j = 0; j < 4; ++j) v = fmaxf(v, 2.f * acc[i][j][r] - k2v[j]);
        for (int m = 8; m; m >>= 1) v = fmaxf(v, __shfl_xor(v, m));
        if (l15 == 0) wm[wr + i * 16 + quad * 4 + r][wave & 1] = v;
      }
    __syncthreads();                 // wm publish (also: all Bs reads complete)
    if (t < 128) {
      const float tmax = fmaxf(wm[t][0], wm[t][1]);
      lmax = fmaxf(lmax, tmax);
      atomicMax(&rowmax[bm * 128 + t], enc_f32(lmax));     // fire-and-forget: no return wait
      thr[t] = fmaxf(lmax, dec_f32(rstale)) - MARGIN;      // dec(0-init)=NaN; fmaxf drops it
    }
    __syncthreads();                 // thr publish
    // pushes: thr via ds_read (no DMA pending), LDS counter, per-(row,cg) segment
#pragma unroll
    for (int i = 0; i < 4; ++i)
#pragma unroll
      for (int r = 0; r < 4; ++r) {
        const int rl = wr + i * 16 + quad * 4 + r;
        const float th = thr[rl];
#pragma unroll
        for (int j = 0; j < 4; ++j) {
          const float s = 2.f * acc[i][j][r] - k2v[j];
          if (s >= th) {
            const int n = cg * 4096 + tile * 128 + wc + j * 16 + l15;
            const int pos = atomicAdd(&pcnt[rl], 1);
            if (pos < SLOT)
              cand[((size_t)(bm * 128 + rl) * 8 + cg) * SLOT + pos] = pack_cand(s, n);
          }
        }
      }
#pragma unroll
    for (int i = 0; i < 4; ++i)
#pragma unroll
      for (int j = 0; j < 4; ++j)
#pragma unroll
        for (int r2 = 0; r2 < 4; ++r2) acc[i][j][r2] = 0.f;
    // stage next B tile LAST: nothing follows except the loop-top barrier
    if (tile + 1 < 32) {
      const unsigned short* gB = kbf + ((size_t)cg * 4096 + (size_t)(tile + 1) * 128 + srow) * DKDIM + scg * 8;
#pragma unroll
      for (int ks = 0; ks < 8; ++ks) {
        gld16(gB + ks * 32,                      Bs + ks * 4096 + t * 8);
        gld16(gB + (size_t)64 * DKDIM + ks * 32, Bs + ks * 4096 + 2048 + t * 8);
      }
    }
  }
  __syncthreads();
  if (t < 128) cnt[(size_t)(bm * 128 + t) * 8 + cg] = min(pcnt[t], SLOT);
}

// ---------------------------------------------------------------- two-stage filter + exact recursion
// (R1 harness-passed version: gathers 8 per-(row,cg) segments)
__global__ __launch_bounds__(256) void knn_rounds(const float* __restrict__ qf,
                                                  const float* __restrict__ keys,
                                                  const float* __restrict__ k2,
                                                  const float* __restrict__ vals,
                                                  const int* __restrict__ cnt,
                                                  const unsigned* __restrict__ cand,
                                                  unsigned short* __restrict__ nearest) {
  __shared__ __align__(16) float qs[DKDIM];
  __shared__ unsigned cl[CAPS];
  __shared__ float red[256];
  __shared__ int   sidx[SURV];
  __shared__ float Ls[SURV];
  __shared__ int   sidx2[SURV2];
  __shared__ float L2v[SURV2];
  __shared__ float cs[SURV2];
  __shared__ float Ws[SURV2 * KN];
  __shared__ int n1, n2;
  const int row = blockIdx.x, t = threadIdx.x;
  qs[t] = qf[(size_t)row * DKDIM + t];
  if (t == 0) { n1 = 0; n2 = 0; }
  float m = -3.4e38f;
  int C = 0;
  for (int s8 = 0; s8 < 8; ++s8) {              // gather the 8 per-slice segments
    const int Cs = min(cnt[(size_t)row * 8 + s8], SLOT);
    const unsigned* cp = cand + ((size_t)row * 8 + s8) * SLOT;
    for (int i = t; i < Cs; i += 256) {
      const unsigned p = cp[i];
      cl[C + i] = p;
      m = fmaxf(m, cand_score(p));
    }
    C += Cs;                                    // uniform across threads
  }
  red[t] = m;
  __syncthreads();
  for (int s = 128; s; s >>= 1) {
    if (t < s) red[t] = fmaxf(red[t], red[t + s]);
    __syncthreads();
  }
  // stage 1: approx-score filter (deterministic set; cap proven unreachable)
  const float th1 = red[0] - REFILT_M;
  for (int i = t; i < C; i += 256) {
    if (cand_score(cl[i]) >= th1) {
      const int p = atomicAdd(&n1, 1);
      if (p < SURV) sidx[p] = (int)(cl[i] & 32767u);
    }
  }
  if (t < SURV2) cs[t] = 0.f;
  __syncthreads();
  const int S1 = min(n1, SURV);
  // exact fp32 logits for stage-1 survivors (q2 dropped: softmax shift-invariant)
  const int wv = t >> 6, ln = t & 63;
  for (int i = wv; i < S1; i += 4) {
    const int n = sidx[i];
    const float4 kv = *(const float4*)(keys + (size_t)n * DKDIM + ln * 4);
    const float4 qv = *(const float4*)(qs + ln * 4);
    float d = kv.x * qv.x + kv.y * qv.y + kv.z * qv.z + kv.w * qv.w;
    for (int o = 32; o; o >>= 1) d += __shfl_down(d, o);
    if (ln == 0) Ls[i] = (2.f * d - k2[n]) / 0.1f;
  }
  __syncthreads();
  red[t] = (t < S1) ? Ls[t] : -3.4e38f;
  __syncthreads();
  for (int s = 128; s; s >>= 1) {
    if (t < s) red[t] = fmaxf(red[t], red[t + s]);
    __syncthreads();
  }
  // stage 2: exact-logit filter at rigorous depth
  const float Lmax = red[0];
  if (t < S1 && Ls[t] >= Lmax - EXACT_M) {
    const int p = atomicAdd(&n2, 1);
    if (p < SURV2) { sidx2[p] = sidx[t]; L2v[p] = Ls[t]; }
  }
  __syncthreads();
  const int S2 = min(n2, SURV2);
  if (t < 64) {  // wave 0 runs the recursion (S2 small)
    for (int j = 0; j < KN; ++j) {
      float lm = -3.4e38f;
      for (int i = t; i < S2; i += 64) lm = fmaxf(lm, L2v[i] + cs[i]);
      for (int o = 32; o; o >>= 1) lm = fmaxf(lm, __shfl_xor(lm, o));
      float zs = 0.f;
      for (int i = t; i < S2; i += 64) {
        const float e = expf(L2v[i] + cs[i] - lm);
        Ws[i * KN + j] = e; zs += e;
      }
      for (int o = 32; o; o >>= 1) zs += __shfl_xor(zs, o);
      const float Zi = 1.f / zs;
      for (int i = t; i < S2; i += 64) {
        const float w = Ws[i * KN + j] * Zi;
        Ws[i * KN + j] = w;
        cs[i] += log1pf(1e-6f - w);
      }
    }
  }
  __syncthreads();
  // one pass over stage-2 vals rows for all 8 rounds
  float acc[KN] = {};
  for (int i = 0; i < S2; ++i) {
    const float v = vals[(size_t)sidx2[i] * DMDIM + t];
#pragma unroll
    for (int j = 0; j < KN; ++j) acc[j] += Ws[i * KN + j] * v;
  }
#pragma unroll
  for (int j = 0; j < KN; ++j)
    nearest[(size_t)row * FDIM + j * DMDIM + t] = f2bf(acc[j]);
}

// ---------------------------------------------------------------- out = nearest @ W_out^T + b_out
__global__ __launch_bounds__(256) void out_gemm(const unsigned short* __restrict__ nbf,
                                                const unsigned short* __restrict__ wbf,
                                                const float* __restrict__ bout,
                                                float* __restrict__ out) {
  __shared__ __align__(16) unsigned short As[4096];
  __shared__ __align__(16) unsigned short Bs[4096];
  f32x4 acc[4][4] = {};
  gemm_tile<FDIM>(nbf, wbf, blockIdx.x, blockIdx.y, As, Bs, acc);
  const int lane = threadIdx.x & 63, wave = threadIdx.x >> 6;
  const int quad = lane >> 4, l15 = lane & 15;
  const int wr = (wave >> 1) * 64, wc = (wave & 1) * 64;
#pragma unroll
  for (int i = 0; i < 4; ++i)
#pragma unroll
    for (int r = 0; r < 4; ++r) {
      const int gm = blockIdx.x * 128 + wr + i * 16 + quad * 4 + r;
#pragma unroll
      for (int j = 0; j < 4; ++j) {
        const int n = blockIdx.y * 128 + wc + j * 16 + l15;
        out[(size_t)gm * DDIM + n] = acc[i][j][r] + bout[n];
      }
    }
}

// ---------------------------------------------------------------- RMSNorm epilogue (in-place)
__global__ __launch_bounds__(256) void rmsnorm(float* __restrict__ out,
                                               const float* __restrict__ rmsw) {
  __shared__ float red[256];
  const int row = blockIdx.x, t = threadIdx.x;
  const float4 v = *(const float4*)(out + (size_t)row * DDIM + t * 4);
  red[t] = v.x * v.x + v.y * v.y + v.z * v.z + v.w * v.w;
  __syncthreads();
  for (int s = 128; s; s >>= 1) {
    if (t < s) red[t] += red[t + s];
    __syncthreads();
  }
  const float scale = rsqrtf(red[0] / (float)DDIM + 1e-6f);
  const float4 w = *(const float4*)(rmsw + t * 4);
  float4 o;
  o.x = v.x * scale * w.x; o.y = v.y * scale * w.y;
  o.z = v.z * scale * w.z; o.w = v.w * scale * w.w;
  *(float4*)(out + (size_t)row * DDIM + t * 4) = o;
}

extern "C" void kernel_launch(void* const* d_in, const int* in_sizes, int n_in,
                              void* d_out, int out_size, void* d_ws, size_t ws_size,
                              hipStream_t stream) {
  const float* x    = (const float*)d_in[0];
  const float* keys = (const float*)d_in[1];
  const float* vals = (const float*)d_in[2];
  const float* Win  = (const float*)d_in[3];
  const float* bin  = (const float*)d_in[4];
  const float* Wout = (const float*)d_in[5];
  const float* bout = (const float*)d_in[6];
  const float* rmsw = (const float*)d_in[7];
  float* out = (float*)d_out;
  char* ws = (char*)d_ws;

  // workspace layout (total ~49.3 MB; R1 segment layout)
  float*          q_f32   = (float*)(ws);                       // 4 MB
  unsigned short* q_bf    = (unsigned short*)(ws + 4194304);    // 2 MB
  unsigned short* k_bf    = (unsigned short*)(ws + 6291456);    // 16 MB (dead after score_select)
  unsigned short* nearest = (unsigned short*)(ws + 6291456);    // 16 MB overlay on k_bf
  float*          k2      = (float*)(ws + 23068672);            // 128 KB
  unsigned*       rowmax  = (unsigned*)(ws + 23199744);         // 16 KB
  int*            cnt     = (int*)(ws + 23216128);              // 128 KB (4096 rows x 8 slices)
  unsigned*       cand    = (unsigned*)(ws + 23347200);         // 23 MB (4096*8*184*4)
  unsigned short* w_bf    = (unsigned short*)(ws + 47464448);   // 4 MB -> end 51658752

  prep_all<<<10256, 256, 0, stream>>>(keys, Wout, k_bf, k2, w_bf, rowmax);
  qproj<<<dim3(ROWS / 64, DKDIM / 64), 256, 0, stream>>>(x, Win, bin, q_f32, q_bf);
  score_select<<<dim3(8, 32), 256, 0, stream>>>(q_bf, k_bf, k2, rowmax, cnt, cand);
  knn_rounds<<<ROWS, 256, 0, stream>>>(q_f32, keys, k2, vals, cnt, cand, nearest);
  out_gemm<<<dim3(ROWS / 128, DDIM / 128), 256, 0, stream>>>(nearest, w_bf, bout, out);
  rmsnorm<<<ROWS, 256, 0, stream>>>(out, rmsw);
}

// Round 11
// 426.104 us; speedup vs baseline: 1.2455x; 1.2455x over previous
//
#include <hip/hip_runtime.h>
#include <hip/hip_bf16.h>

// Problem constants
#define ROWS  4096      // B*T
#define DDIM  1024
#define DKDIM 256
#define NKEYS 32768
#define DMDIM 256
#define KN    8
#define FDIM  2048      // KN*DM
#define CAPS  1536      // pushed-candidate cap per row (measured ~540/row)
#define SURV  128       // stage-1 survivors (mean ~30 at 12.25, max << 128)
#define SURV2 96        // stage-2 survivors (mean ~21)
#define MARGIN   16.0f  // push margin, s-units (proven R2 value)
#define REFILT_M 12.25f // stage-1: 10.82 exact depth + 1.2 bf16 err + 0.05 quant
#define EXACT_M  109.0f // stage-2, logit units: 7*13.8 + ln(1e5)

typedef float  f32x4  __attribute__((ext_vector_type(4)));
typedef __bf16 bf16x8 __attribute__((ext_vector_type(8)));

static __device__ __forceinline__ unsigned enc_f32(float f) {
  unsigned u = __float_as_uint(f);
  return u ^ ((unsigned)((int)u >> 31) | 0x80000000u);
}
static __device__ __forceinline__ float dec_f32(unsigned u) {
  unsigned b = (u & 0x80000000u) ? (u ^ 0x80000000u) : ~u;
  return __uint_as_float(b);
}
static __device__ __forceinline__ unsigned short f2bf(float f) {
  unsigned u = __float_as_uint(f);
  u += 0x7FFFu + ((u >> 16) & 1u);          // RNE truncate to bf16
  return (unsigned short)(u >> 16);
}
// pack candidate: score quantized (1/64 res) high, key id (15 bits) low
static __device__ __forceinline__ unsigned pack_cand(float s, int n) {
  float q = (s + 1024.f) * 64.f;
  int u = (int)q;
  u = u < 0 ? 0 : (u > 131071 ? 131071 : u);
  return ((unsigned)u << 15) | (unsigned)n;
}
static __device__ __forceinline__ float cand_score(unsigned p) {
  return (float)(p >> 15) * (1.f / 64.f) - 1024.f;
}
static __device__ __forceinline__ void gld16(const void* g, void* l) {
  __builtin_amdgcn_global_load_lds((const __attribute__((address_space(1))) void*)g,
                                   (__attribute__((address_space(3))) void*)l, 16, 0, 0);
}

// ---------------------------------------------------------------- fused prep:
// blocks [0,8192): keys->bf16 + k2 ; [8192,10240): Wout->bf16 ; [10240,10272): zero rowmax+cnt
__global__ __launch_bounds__(256) void prep_all(const float* __restrict__ keys,
                                                const float* __restrict__ Wout,
                                                unsigned short* __restrict__ kbf,
                                                float* __restrict__ k2,
                                                unsigned short* __restrict__ wbf,
                                                unsigned* __restrict__ rowmax) {
  const int b = blockIdx.x, t = threadIdx.x;
  if (b < 8192) {
    const int row = b * 4 + (t >> 6);
    const int ln  = t & 63;
    const float4 v = *(const float4*)(keys + (size_t)row * DKDIM + ln * 4);
    ushort4 o;
    o.x = f2bf(v.x); o.y = f2bf(v.y); o.z = f2bf(v.z); o.w = f2bf(v.w);
    *(ushort4*)(kbf + (size_t)row * DKDIM + ln * 4) = o;
    float ss = v.x*v.x + v.y*v.y + v.z*v.z + v.w*v.w;
    for (int off = 32; off; off >>= 1) ss += __shfl_down(ss, off);
    if (ln == 0) k2[row] = ss;
  } else if (b < 10240) {
    const int i = (b - 8192) * 256 + t;      // i < 524288 = DDIM*FDIM/4
    const float4 v = *(const float4*)(Wout + (size_t)i * 4);
    ushort4 o;
    o.x = f2bf(v.x); o.y = f2bf(v.y); o.z = f2bf(v.z); o.w = f2bf(v.w);
    *(ushort4*)(wbf + (size_t)i * 4) = o;
  } else {
    rowmax[(b - 10240) * 256 + t] = 0u;      // zeroes rowmax(4096) + cnt(4096)
  }
}

// ---------------------------------------------------------------- q = x @ W_in^T + b_in (fp32)
__global__ __launch_bounds__(256) void qproj(const float* __restrict__ x,
                                             const float* __restrict__ Win,
                                             const float* __restrict__ bin,
                                             float* __restrict__ qf,
                                             unsigned short* __restrict__ qbf) {
  __shared__ __align__(16) float As[64][68];
  __shared__ __align__(16) float Bs[64][68];
  const int bm = blockIdx.x, bn = blockIdx.y;
  const int t  = threadIdx.x;
  const int tx = t & 15, ty = t >> 4;
  float acc[4][4] = {};
  for (int ks = 0; ks < 16; ++ks) {
    __syncthreads();
    for (int l = t; l < 1024; l += 256) {
      const int row = l >> 4, kc = l & 15;
      *(float4*)(&As[row][kc * 4]) =
          *(const float4*)(x + (size_t)(bm * 64 + row) * DDIM + ks * 64 + kc * 4);
      *(float4*)(&Bs[row][kc * 4]) =
          *(const float4*)(Win + (size_t)(bn * 64 + row) * DDIM + ks * 64 + kc * 4);
    }
    __syncthreads();
    for (int kk = 0; kk < 64; kk += 4) {
      float4 av[4], bv[4];
#pragma unroll
      for (int i = 0; i < 4; ++i) av[i] = *(const float4*)(&As[ty * 4 + i][kk]);
#pragma unroll
      for (int j = 0; j < 4; ++j) bv[j] = *(const float4*)(&Bs[tx * 4 + j][kk]);
#pragma unroll
      for (int i = 0; i < 4; ++i)
#pragma unroll
        for (int j = 0; j < 4; ++j)
          acc[i][j] += av[i].x * bv[j].x + av[i].y * bv[j].y +
                       av[i].z * bv[j].z + av[i].w * bv[j].w;
    }
  }
#pragma unroll
  for (int i = 0; i < 4; ++i)
#pragma unroll
    for (int j = 0; j < 4; ++j) {
      const int m = bm * 64 + ty * 4 + i, n = bn * 64 + tx * 4 + j;
      const float q = acc[i][j] + bin[n];
      qf[(size_t)m * DKDIM + n] = q;
      qbf[(size_t)m * DKDIM + n] = f2bf(q);
    }
}

// ---------------------------------------------------------------- shared MFMA tile
// R8-verified: single-buffer, 2 barriers/chunk + zero-register slot-XOR swizzle
// (SQ_LDS_BANK_CONFLICT 8.4M -> 0, coalescing unchanged, VGPR 84, ~2-3 blocks/CU).
template <int KD>
static __device__ __forceinline__ void gemm_tile(const unsigned short* __restrict__ A,
                                                 const unsigned short* __restrict__ B,
                                                 int bm, int bn,
                                                 unsigned short* As, unsigned short* Bs,
                                                 f32x4 acc[4][4]) {
  const int tid  = threadIdx.x;
  const int lane = tid & 63, wave = tid >> 6;
  const int quad = lane >> 4, l15 = lane & 15;
  const int wr = (wave >> 1) * 64, wc = (wave & 1) * 64;
  const int srow = tid >> 2;
  const int scg  = (tid & 3) ^ ((srow >> 1) & 3);        // swizzled source slot
  const int qa   = quad ^ ((l15 >> 1) & 3);              // swizzled read slot
  const unsigned short* gA = A + (size_t)(bm * 128 + srow) * KD + scg * 8;
  const unsigned short* gB = B + (size_t)(bn * 128 + srow) * KD + scg * 8;
  for (int ks = 0; ks < KD / 32; ++ks) {
    __syncthreads();
    gld16(gA + ks * 32,                     As + tid * 8);
    gld16(gA + (size_t)64 * KD + ks * 32,   As + 2048 + tid * 8);
    gld16(gB + ks * 32,                     Bs + tid * 8);
    gld16(gB + (size_t)64 * KD + ks * 32,   Bs + 2048 + tid * 8);
    __syncthreads();
    bf16x8 af[4], bfr[4];
#pragma unroll
    for (int i = 0; i < 4; ++i)
      af[i] = *(const bf16x8*)(As + (wr + i * 16 + l15) * 32 + qa * 8);
#pragma unroll
    for (int j = 0; j < 4; ++j)
      bfr[j] = *(const bf16x8*)(Bs + (wc + j * 16 + l15) * 32 + qa * 8);
#pragma unroll
    for (int i = 0; i < 4; ++i)
#pragma unroll
      for (int j = 0; j < 4; ++j)
        acc[i][j] = __builtin_amdgcn_mfma_f32_16x16x32_bf16(af[i], bfr[j], acc[i][j], 0, 0, 0);
  }
}

// ---------------------------------------------------------------- fused score + select (R8 + T1 XCD swizzle)
// R8 epilogue verbatim. Only change: bijective XCD-aware block remap. Default dispatch
// round-robins consecutive linear blocks (same bn, varying bm) across the 8 XCDs, so every
// XCD pulls all 16MB of kbf through its private 4MB L2. Remap linear id column-major with
// xcd = lin&7 owning bn in [xcd*32, xcd*32+32): per-XCD working set = 2MB kbf slice + 2MB
// qbf = exactly its L2. Staging gld16s become L2-hits instead of L3-hits -> attacks the
// exposed drain latency directly (kernel is latency-bound: 517 GB/s, MfmaUtil 19%).
__global__ __launch_bounds__(256) void score_select(const unsigned short* __restrict__ qbf,
                                                    const unsigned short* __restrict__ kbf,
                                                    const float* __restrict__ k2,
                                                    unsigned* __restrict__ rowmax,
                                                    int* __restrict__ cnt,
                                                    unsigned* __restrict__ cand) {
  __shared__ __align__(16) unsigned short As[4096];
  __shared__ __align__(16) unsigned short Bs[4096];
  __shared__ float wm[128][2];
  __shared__ float thr[128];
  // T1: linear id -> (bm, bn) column-major per-XCD (8192 = 8 XCDs x 1024)
  const unsigned lin = blockIdx.x + blockIdx.y * gridDim.x;
  const unsigned cm  = (lin & 7) * 1024 + (lin >> 3);
  const int bm = (int)(cm & 31), bn = (int)(cm >> 5);
  f32x4 acc[4][4] = {};
  gemm_tile<DKDIM>(qbf, kbf, bm, bn, As, Bs, acc);
  const int t = threadIdx.x;
  const int lane = t & 63, wave = t >> 6;
  const int quad = lane >> 4, l15 = lane & 15;
  const int wr = (wave >> 1) * 64, wc = (wave & 1) * 64;
  float k2v[4];
#pragma unroll
  for (int j = 0; j < 4; ++j) k2v[j] = k2[bn * 128 + wc + j * 16 + l15];
  // per-wave row maxes -> LDS
#pragma unroll
  for (int i = 0; i < 4; ++i)
#pragma unroll
    for (int r = 0; r < 4; ++r) {
      float v = -3.4e38f;
#pragma unroll
      for (int j = 0; j < 4; ++j) v = fmaxf(v, 2.f * acc[i][j][r] - k2v[j]);
      for (int m = 8; m; m >>= 1) v = fmaxf(v, __shfl_xor(v, m));
      if (l15 == 0) wm[wr + i * 16 + quad * 4 + r][wave & 1] = v;
    }
  __syncthreads();
  if (t < 128) {
    const float tile = fmaxf(wm[t][0], wm[t][1]);
    const unsigned old = atomicMax(&rowmax[bm * 128 + t], enc_f32(tile));
    thr[t] = fmaxf(tile, dec_f32(old)) - MARGIN;   // dec(0-init)=NaN; fmaxf drops it
  }
  __syncthreads();
#pragma unroll
  for (int i = 0; i < 4; ++i)
#pragma unroll
    for (int r = 0; r < 4; ++r) {
      const int rl = wr + i * 16 + quad * 4 + r;
      const float th = thr[rl];
      const int gm = bm * 128 + rl;
#pragma unroll
      for (int j = 0; j < 4; ++j) {
        const float s = 2.f * acc[i][j][r] - k2v[j];
        if (s >= th) {
          const int n = bn * 128 + wc + j * 16 + l15;
          const int pos = atomicAdd(&cnt[gm], 1);
          if (pos < CAPS) cand[(size_t)gm * CAPS + pos] = pack_cand(s, n);
        }
      }
    }
}

// ---------------------------------------------------------------- two-stage filter + exact recursion
__global__ __launch_bounds__(256) void knn_rounds(const float* __restrict__ qf,
                                                  const float* __restrict__ keys,
                                                  const float* __restrict__ k2,
                                                  const float* __restrict__ vals,
                                                  const int* __restrict__ cnt,
                                                  const unsigned* __restrict__ cand,
                                                  unsigned short* __restrict__ nearest) {
  __shared__ __align__(16) float qs[DKDIM];
  __shared__ unsigned cl[CAPS];
  __shared__ float red[256];
  __shared__ int   sidx[SURV];
  __shared__ float Ls[SURV];
  __shared__ int   sidx2[SURV2];
  __shared__ float L2v[SURV2];
  __shared__ float cs[SURV2];
  __shared__ float Ws[SURV2 * KN];
  __shared__ int n1, n2;
  const int row = blockIdx.x, t = threadIdx.x;
  const int C = min(cnt[row], CAPS);
  qs[t] = qf[(size_t)row * DKDIM + t];
  if (t == 0) { n1 = 0; n2 = 0; }
  float m = -3.4e38f;
  for (int i = t; i < C; i += 256) {
    const unsigned p = cand[(size_t)row * CAPS + i];
    cl[i] = p;
    m = fmaxf(m, cand_score(p));
  }
  red[t] = m;
  __syncthreads();
  for (int s = 128; s; s >>= 1) {
    if (t < s) red[t] = fmaxf(red[t], red[t + s]);
    __syncthreads();
  }
  // stage 1: approx-score filter (deterministic set; cap proven unreachable)
  const float th1 = red[0] - REFILT_M;
  for (int i = t; i < C; i += 256) {
    if (cand_score(cl[i]) >= th1) {
      const int p = atomicAdd(&n1, 1);
      if (p < SURV) sidx[p] = (int)(cl[i] & 32767u);
    }
  }
  if (t < SURV2) cs[t] = 0.f;
  __syncthreads();
  const int S1 = min(n1, SURV);
  // exact fp32 logits for stage-1 survivors (q2 dropped: softmax shift-invariant)
  const int wv = t >> 6, ln = t & 63;
  for (int i = wv; i < S1; i += 4) {
    const int n = sidx[i];
    const float4 kv = *(const float4*)(keys + (size_t)n * DKDIM + ln * 4);
    const float4 qv = *(const float4*)(qs + ln * 4);
    float d = kv.x * qv.x + kv.y * qv.y + kv.z * qv.z + kv.w * qv.w;
    for (int o = 32; o; o >>= 1) d += __shfl_down(d, o);
    if (ln == 0) Ls[i] = (2.f * d - k2[n]) / 0.1f;
  }
  __syncthreads();
  red[t] = (t < S1) ? Ls[t] : -3.4e38f;
  __syncthreads();
  for (int s = 128; s; s >>= 1) {
    if (t < s) red[t] = fmaxf(red[t], red[t + s]);
    __syncthreads();
  }
  // stage 2: exact-logit filter at rigorous depth
  const float Lmax = red[0];
  if (t < S1 && Ls[t] >= Lmax - EXACT_M) {
    const int p = atomicAdd(&n2, 1);
    if (p < SURV2) { sidx2[p] = sidx[t]; L2v[p] = Ls[t]; }
  }
  __syncthreads();
  const int S2 = min(n2, SURV2);
  if (t < 64) {  // wave 0 runs the recursion (S2 small)
    for (int j = 0; j < KN; ++j) {
      float lm = -3.4e38f;
      for (int i = t; i < S2; i += 64) lm = fmaxf(lm, L2v[i] + cs[i]);
      for (int o = 32; o; o >>= 1) lm = fmaxf(lm, __shfl_xor(lm, o));
      float zs = 0.f;
      for (int i = t; i < S2; i += 64) {
        const float e = expf(L2v[i] + cs[i] - lm);
        Ws[i * KN + j] = e; zs += e;
      }
      for (int o = 32; o; o >>= 1) zs += __shfl_xor(zs, o);
      const float Zi = 1.f / zs;
      for (int i = t; i < S2; i += 64) {
        const float w = Ws[i * KN + j] * Zi;
        Ws[i * KN + j] = w;
        cs[i] += log1pf(1e-6f - w);
      }
    }
  }
  __syncthreads();
  // one pass over stage-2 vals rows for all 8 rounds
  float acc[KN] = {};
  for (int i = 0; i < S2; ++i) {
    const float v = vals[(size_t)sidx2[i] * DMDIM + t];
#pragma unroll
    for (int j = 0; j < KN; ++j) acc[j] += Ws[i * KN + j] * v;
  }
#pragma unroll
  for (int j = 0; j < KN; ++j)
    nearest[(size_t)row * FDIM + j * DMDIM + t] = f2bf(acc[j]);
}

// ---------------------------------------------------------------- out = nearest @ W_out^T + b_out
__global__ __launch_bounds__(256) void out_gemm(const unsigned short* __restrict__ nbf,
                                                const unsigned short* __restrict__ wbf,
                                                const float* __restrict__ bout,
                                                float* __restrict__ out) {
  __shared__ __align__(16) unsigned short As[4096];
  __shared__ __align__(16) unsigned short Bs[4096];
  f32x4 acc[4][4] = {};
  gemm_tile<FDIM>(nbf, wbf, blockIdx.x, blockIdx.y, As, Bs, acc);
  const int lane = threadIdx.x & 63, wave = threadIdx.x >> 6;
  const int quad = lane >> 4, l15 = lane & 15;
  const int wr = (wave >> 1) * 64, wc = (wave & 1) * 64;
#pragma unroll
  for (int i = 0; i < 4; ++i)
#pragma unroll
    for (int r = 0; r < 4; ++r) {
      const int gm = blockIdx.x * 128 + wr + i * 16 + quad * 4 + r;
#pragma unroll
      for (int j = 0; j < 4; ++j) {
        const int n = blockIdx.y * 128 + wc + j * 16 + l15;
        out[(size_t)gm * DDIM + n] = acc[i][j][r] + bout[n];
      }
    }
}

// ---------------------------------------------------------------- RMSNorm epilogue (in-place)
__global__ __launch_bounds__(256) void rmsnorm(float* __restrict__ out,
                                               const float* __restrict__ rmsw) {
  __shared__ float red[256];
  const int row = blockIdx.x, t = threadIdx.x;
  const float4 v = *(const float4*)(out + (size_t)row * DDIM + t * 4);
  red[t] = v.x * v.x + v.y * v.y + v.z * v.z + v.w * v.w;
  __syncthreads();
  for (int s = 128; s; s >>= 1) {
    if (t < s) red[t] += red[t + s];
    __syncthreads();
  }
  const float scale = rsqrtf(red[0] / (float)DDIM + 1e-6f);
  const float4 w = *(const float4*)(rmsw + t * 4);
  float4 o;
  o.x = v.x * scale * w.x; o.y = v.y * scale * w.y;
  o.z = v.z * scale * w.z; o.w = v.w * scale * w.w;
  *(float4*)(out + (size_t)row * DDIM + t * 4) = o;
}

extern "C" void kernel_launch(void* const* d_in, const int* in_sizes, int n_in,
                              void* d_out, int out_size, void* d_ws, size_t ws_size,
                              hipStream_t stream) {
  const float* x    = (const float*)d_in[0];
  const float* keys = (const float*)d_in[1];
  const float* vals = (const float*)d_in[2];
  const float* Win  = (const float*)d_in[3];
  const float* bin  = (const float*)d_in[4];
  const float* Wout = (const float*)d_in[5];
  const float* bout = (const float*)d_in[6];
  const float* rmsw = (const float*)d_in[7];
  float* out = (float*)d_out;
  char* ws = (char*)d_ws;

  // workspace layout (total ~52.6 MB)
  float*          q_f32   = (float*)(ws);                       // 4 MB
  unsigned short* q_bf    = (unsigned short*)(ws + 4194304);    // 2 MB
  unsigned short* k_bf    = (unsigned short*)(ws + 6291456);    // 16 MB (dead after score_select)
  unsigned short* nearest = (unsigned short*)(ws + 6291456);    // 16 MB overlay on k_bf
  float*          k2      = (float*)(ws + 23068672);            // 128 KB
  unsigned*       rowmax  = (unsigned*)(ws + 23199744);         // 16 KB
  int*            cnt     = (int*)(ws + 23216128);              // 16 KB (contiguous after rowmax)
  unsigned*       cand    = (unsigned*)(ws + 23232512);         // 24 MB (4096*1536*4)
  unsigned short* w_bf    = (unsigned short*)(ws + 48398336);   // 4 MB

  prep_all<<<10272, 256, 0, stream>>>(keys, Wout, k_bf, k2, w_bf, rowmax);
  qproj<<<dim3(ROWS / 64, DKDIM / 64), 256, 0, stream>>>(x, Win, bin, q_f32, q_bf);
  score_select<<<dim3(ROWS / 128, NKEYS / 128), 256, 0, stream>>>(q_bf, k_bf, k2, rowmax, cnt, cand);
  knn_rounds<<<ROWS, 256, 0, stream>>>(q_f32, keys, k2, vals, cnt, cand, nearest);
  out_gemm<<<dim3(ROWS / 128, DDIM / 128), 256, 0, stream>>>(nearest, w_bf, bout, out);
  rmsnorm<<<ROWS, 256, 0, stream>>>(out, rmsw);
}